// Round 5
// baseline (35.267 us; speedup 1.0000x reference)
//
#include <hip/hip_runtime.h>
#include <hip/hip_bf16.h>
#include <math.h>

// Problem: B=8, H=W=256, C=10 metric channels, all fp32.
// ws float layout: [0..255] = per-block partial maxes of mass;
//                  [1024 .. 1024+8*257*10) = per-batch LUT of T(mass), stride 10.
#define GH 256
#define GW 256
#define NC 10
#define NKNOT 257

__device__ __forceinline__ float gelu_exact(float x) {
    return 0.5f * x * (1.0f + erff(x * 0.70710678118654752f));
}
__device__ __forceinline__ float softplus_f(float x) {
    if (x > 20.f) return x;
    return log1pf(expf(x));
}

// ---- Kernel 1: blocks 0..513 build LUT (one wave per (batch,knot));
//      blocks 514..769 compute partial max of mass (float4 loads).
__global__ __launch_bounds__(256) void k_pre(
        const float* __restrict__ mass,
        const float* __restrict__ vel,
        const float* __restrict__ e_w1, const float* __restrict__ e_b1,
        const float* __restrict__ e_w2, const float* __restrict__ e_b2,
        const float* __restrict__ m_w1, const float* __restrict__ m_b1,
        const float* __restrict__ m_w2, const float* __restrict__ m_b2,
        const float* __restrict__ s_w1, const float* __restrict__ s_b1,
        const float* __restrict__ s_w2, const float* __restrict__ s_b2,
        float* __restrict__ ws) {
    const int tid = threadIdx.x;
    if (blockIdx.x >= 514) {  // ---- partial max over mass
        const int pb = blockIdx.x - 514;           // 0..255
        const float4* mass4 = (const float4*)mass; // 131072 float4 total
        int base = pb * 512 + tid;                 // 512 float4 per block
        float4 a = mass4[base];
        float4 c = mass4[base + 256];
        float v = fmaxf(fmaxf(fmaxf(a.x, a.y), fmaxf(a.z, a.w)),
                        fmaxf(fmaxf(c.x, c.y), fmaxf(c.z, c.w)));
        #pragma unroll
        for (int off = 32; off > 0; off >>= 1)
            v = fmaxf(v, __shfl_xor(v, off, 64));
        __shared__ float sred[4];
        if ((tid & 63) == 0) sred[tid >> 6] = v;
        __syncthreads();
        if (tid == 0)
            ws[pb] = fmaxf(fmaxf(sred[0], sred[1]), fmaxf(sred[2], sred[3]));
        return;
    }
    // ---- LUT build: wave-parallel over hidden dim
    const int wave = blockIdx.x * 4 + (tid >> 6);   // 0..2055 == 8*257-1
    const int lane = tid & 63;
    const int b = wave / NKNOT, knot = wave % NKNOT;
    const float m = (float)knot * (1.0f / 256.0f);
    const float vx = vel[b * 3 + 0], vy = vel[b * 3 + 1], vz = vel[b * 3 + 2];

    float acc[10];
    {   // energy hidden unit `lane`
        float pre = m * e_w1[lane] + vx * e_w1[64 + lane] + vy * e_w1[128 + lane]
                  + vz * e_w1[192 + lane] + e_b1[lane];
        acc[0] = gelu_exact(pre) * e_w2[lane];
    }
    {   // momentum hidden unit `lane`
        float pre = m * m_w1[lane] + vx * m_w1[64 + lane] + vy * m_w1[128 + lane]
                  + vz * m_w1[192 + lane] + m_b1[lane];
        float h = gelu_exact(pre);
        acc[1] = h * m_w2[lane * 3 + 0];
        acc[2] = h * m_w2[lane * 3 + 1];
        acc[3] = h * m_w2[lane * 3 + 2];
    }
    {   // stress hidden units `lane`, `lane+64`
        float pre0 = m * s_w1[lane] + vx * s_w1[128 + lane] + vy * s_w1[256 + lane]
                   + vz * s_w1[384 + lane] + s_b1[lane];
        float pre1 = m * s_w1[64 + lane] + vx * s_w1[192 + lane] + vy * s_w1[320 + lane]
                   + vz * s_w1[448 + lane] + s_b1[64 + lane];
        float h0 = gelu_exact(pre0), h1 = gelu_exact(pre1);
        #pragma unroll
        for (int k = 0; k < 6; k++)
            acc[4 + k] = h0 * s_w2[lane * 6 + k] + h1 * s_w2[(lane + 64) * 6 + k];
    }
    #pragma unroll
    for (int c = 0; c < 10; c++) {
        float v = acc[c];
        #pragma unroll
        for (int off = 32; off > 0; off >>= 1)
            v += __shfl_xor(v, off, 64);
        acc[c] = v;
    }
    if (lane == 0) {
        float* lut = ws + 1024 + (size_t)(b * NKNOT + knot) * NC;
        lut[0] = softplus_f(acc[0] + e_b2[0]);
        lut[1] = acc[1] + m_b2[0];
        lut[2] = acc[2] + m_b2[1];
        lut[3] = acc[3] + m_b2[2];
        #pragma unroll
        for (int k = 0; k < 6; k++) lut[4 + k] = acc[4 + k] + s_b2[k];
    }
}

// ---- Kernel 2: 16x16 tile (1024 blocks, 4/CU). ALL global traffic coalesced
// via LDS staging. Region (pre-smooth metric) = 18x18, mass halo tile = 24x24.
__global__ __launch_bounds__(256, 4) void k_main(const float* __restrict__ mass,
                                                 const float* __restrict__ minit,
                                                 const float* __restrict__ solver,
                                                 const float* __restrict__ ws,
                                                 float* __restrict__ out) {
    const int b = blockIdx.z;
    const int tid = threadIdx.x;
    const int tile_x = blockIdx.x * 16, tile_y = blockIdx.y * 16;

    __shared__ float  s_mass[24][24];                 // 2.3 KB, halo 4
    __shared__ float2 s_lut2[NKNOT * 5];              // 10.3 KB, stride 5
    __shared__ float2 s_met2[5][18][18];              // 13.0 KB, halo 1
    __shared__ __align__(16) float2 s_minout[18 * 90];// 13.0 KB: minit, then out
    __shared__ float  s_wmax[4];

    // --- phase 0: all global loads, all coalesced ---
    // finalize global max (256 partials, 1/thread)
    {
        float v = ws[tid];
        #pragma unroll
        for (int off = 32; off > 0; off >>= 1)
            v = fmaxf(v, __shfl_xor(v, off, 64));
        if ((tid & 63) == 0) s_wmax[tid >> 6] = v;
    }
    // LUT: 1285 contiguous float2
    {
        const float2* lutg2 = (const float2*)(ws + 1024 + (size_t)b * NKNOT * NC);
        for (int i = tid; i < NKNOT * 5; i += 256) s_lut2[i] = lutg2[i];
    }
    // minit region 18x18 px: per row an 18-px (180-float) contiguous segment.
    // item-linear float2 copy -> consecutive lanes, consecutive addresses.
    {
        const float* mb = minit + (size_t)b * GH * GW * NC;
        for (int i = tid; i < 18 * 90; i += 256) {
            int r = i / 90, c2 = i % 90;            // c2: float2 within row
            int px = c2 / 5;
            int gy = tile_y - 1 + r, gx = tile_x - 1 + px;
            float2 v = make_float2(0.f, 0.f);
            if ((unsigned)gy < GH && (unsigned)gx < GW)
                v = *(const float2*)(mb + ((size_t)gy * GW + gx) * NC + (c2 % 5) * 2);
            s_minout[i] = v;
        }
    }
    // mass tile 24x24 (12 float2 per row; gx even -> pair all-in or all-out)
    {
        const float* massb = mass + (size_t)b * GH * GW;
        for (int i = tid; i < 24 * 12; i += 256) {
            int my = i / 12, jx = i % 12;
            int gy = tile_y - 4 + my, gx = tile_x - 4 + 2 * jx;
            float2 v = make_float2(0.f, 0.f);
            if ((unsigned)gy < GH && (unsigned)gx < GW)
                v = *(const float2*)(massb + gy * GW + gx);
            *(float2*)&s_mass[my][2 * jx] = v;
        }
    }
    // softmax(solver_params)
    float p0 = solver[0], p1 = solver[1], p2 = solver[2];
    float pm = fmaxf(p0, fmaxf(p1, p2));
    float e0 = expf(p0 - pm), e1 = expf(p1 - pm), e2 = expf(p2 - pm);
    float inv = 1.f / (e0 + e1 + e2);
    float w0 = e0 * inv, w1 = e1 * inv, w2 = e2 * inv;

    __syncthreads();

    const float gmax = fmaxf(fmaxf(s_wmax[0], s_wmax[1]), fmaxf(s_wmax[2], s_wmax[3]));
    const float k0 = -25.132741228718345f * w0;          // w0 * (-8*pi*G/c^4)
    const float potscale = 2.f * w1 / (gmax + 1e-8f);    // folds mass normalization

    // Green weights: GWt[|dy|][|dx|] = -1/(2*pi*r), center 0
    constexpr float GWt[4][4] = {
        {0.f,          -0.15915494f, -0.07957747f, -0.05305165f},
        {-0.15915494f, -0.11253954f, -0.07117625f, -0.05033165f},
        {-0.07957747f, -0.07117625f, -0.05626977f, -0.04414183f},
        {-0.05305165f, -0.05033165f, -0.04414183f, -0.03751318f}};

    // --- stage 2: 9x9 items of 2x2 region pixels (region = 18x18) ---
    for (int item = tid; item < 9 * 9; item += 256) {
        const int py = item / 9, px = item % 9;
        const int ry0 = 2 * py, rx0 = 2 * px;       // rx0 even -> aligned b64
        float potTL = 0.f, potTR = 0.f, potBL = 0.f, potBR = 0.f;
        #pragma unroll
        for (int k = 0; k < 8; k++) {
            const float2* mr = (const float2*)&s_mass[ry0 + k][rx0];
            float v[8];
            #pragma unroll
            for (int h = 0; h < 4; h++) {
                float2 t = mr[h];
                v[2 * h] = t.x; v[2 * h + 1] = t.y;
            }
            #pragma unroll
            for (int j = 0; j < 8; j++) {
                const int dyt = k - 3, dyb = k - 4;
                const int dxl = j - 3, dxr = j - 4;
                const int at = dyt < 0 ? -dyt : dyt, ab = dyb < 0 ? -dyb : dyb;
                const int al = dxl < 0 ? -dxl : dxl, ar = dxr < 0 ? -dxr : dxr;
                if (k <= 6 && j <= 6 && !(k == 3 && j == 3)) potTL += GWt[at][al] * v[j];
                if (k <= 6 && j >= 1 && !(k == 3 && j == 4)) potTR += GWt[at][ar] * v[j];
                if (k >= 1 && j <= 6 && !(k == 4 && j == 3)) potBL += GWt[ab][al] * v[j];
                if (k >= 1 && j >= 1 && !(k == 4 && j == 4)) potBR += GWt[ab][ar] * v[j];
            }
        }
        const float pots[4] = {potTL, potTR, potBL, potBR};
        #pragma unroll
        for (int p = 0; p < 4; p++) {
            const int ry = ry0 + (p >> 1), rx = rx0 + (p & 1);
            const int gy = tile_y + ry - 1, gx = tile_x + rx - 1;
            if ((unsigned)gy >= GH || (unsigned)gx >= GW) {
                #pragma unroll
                for (int cp = 0; cp < 5; cp++)
                    s_met2[cp][ry][rx] = make_float2(0.f, 0.f);
                continue;
            }
            const float m = s_mass[ry + 3][rx + 3];
            const float potterm = potscale * pots[p];
            float x = m * 256.f;
            int i0 = (int)x;
            i0 = i0 < 255 ? i0 : 255;
            const float f = x - (float)i0;
            const float2* L0 = &s_lut2[i0 * 5];
            const float2* L1 = &s_lut2[i0 * 5 + 5];
            const float2* mi2 = &s_minout[(ry * 18 + rx) * 5];
            #pragma unroll
            for (int cp = 0; cp < 5; cp++) {
                float2 t0 = L0[cp], t1 = L1[cp], mi = mi2[cp];
                float2 r;
                r.x = fmaf(k0, fmaf(f, t1.x - t0.x, t0.x), mi.x);
                r.y = fmaf(k0, fmaf(f, t1.y - t0.y, t0.y), mi.y);
                if (cp == 2) r.x += potterm;              // c4
                if (cp == 3) r.y += potterm;              // c7
                if (cp == 0) r.x = fminf(r.x, -0.1f);     // c0
                if (cp == 2) r.x = fmaxf(r.x, 0.1f);      // c4
                if (cp == 3) r.y = fmaxf(r.y, 0.1f);      // c7
                if (cp == 4) r.y = fmaxf(r.y, 0.1f);      // c9
                s_met2[cp][ry][rx] = r;
            }
        }
    }
    __syncthreads();

    // --- stage 3: per-thread output pixel; 3x3 smooth; write to s_out (LDS) ---
    {
        const int oy = tid >> 4, ox = tid & 15;
        float2* s_out2 = s_minout;  // alias: minit no longer needed
        const float g0 = 0.274068619f, g1 = 0.451862761f;
        const bool do_smooth = (w2 > 0.1f);
        #pragma unroll
        for (int cp = 0; cp < 5; cp++) {
            float2 v;
            if (do_smooth) {
                float2 a0 = s_met2[cp][oy][ox],     a1 = s_met2[cp][oy][ox + 1],     a2 = s_met2[cp][oy][ox + 2];
                float2 b0 = s_met2[cp][oy + 1][ox], b1 = s_met2[cp][oy + 1][ox + 1], b2 = s_met2[cp][oy + 1][ox + 2];
                float2 c0 = s_met2[cp][oy + 2][ox], c1 = s_met2[cp][oy + 2][ox + 1], c2 = s_met2[cp][oy + 2][ox + 2];
                float r0x = fmaf(g0, a0.x + a2.x, g1 * a1.x);
                float r0y = fmaf(g0, a0.y + a2.y, g1 * a1.y);
                float r1x = fmaf(g0, b0.x + b2.x, g1 * b1.x);
                float r1y = fmaf(g0, b0.y + b2.y, g1 * b1.y);
                float r2x = fmaf(g0, c0.x + c2.x, g1 * c1.x);
                float r2y = fmaf(g0, c0.y + c2.y, g1 * c1.y);
                v.x = fmaf(g0, r0x + r2x, g1 * r1x);
                v.y = fmaf(g0, r0y + r2y, g1 * r1y);
            } else {
                v = s_met2[cp][oy + 1][ox + 1];
            }
            s_out2[(oy * 16 + ox) * 5 + cp] = v;
        }
    }
    __syncthreads();

    // --- phase 4: coalesced float4 copy s_out -> out (16 rows x 40 float4) ---
    {
        const float4* s_out4 = (const float4*)s_minout;
        float* ob = out + ((size_t)(b * GH + tile_y) * GW + tile_x) * NC;
        for (int i = tid; i < 16 * 40; i += 256) {
            int r = i / 40, c4 = i % 40;
            *(float4*)(ob + (size_t)r * GW * NC + c4 * 4) = s_out4[r * 40 + c4];
        }
    }
}

extern "C" void kernel_launch(void* const* d_in, const int* in_sizes, int n_in,
                              void* d_out, int out_size, void* d_ws, size_t ws_size,
                              hipStream_t stream) {
    const float* mass   = (const float*)d_in[0];
    const float* vel    = (const float*)d_in[1];
    const float* minit  = (const float*)d_in[2];
    const float* e_w1   = (const float*)d_in[3];
    const float* e_b1   = (const float*)d_in[4];
    const float* e_w2   = (const float*)d_in[5];
    const float* e_b2   = (const float*)d_in[6];
    const float* m_w1   = (const float*)d_in[7];
    const float* m_b1   = (const float*)d_in[8];
    const float* m_w2   = (const float*)d_in[9];
    const float* m_b2   = (const float*)d_in[10];
    const float* s_w1   = (const float*)d_in[11];
    const float* s_b1   = (const float*)d_in[12];
    const float* s_w2   = (const float*)d_in[13];
    const float* s_b2   = (const float*)d_in[14];
    const float* solver = (const float*)d_in[15];
    float* ws  = (float*)d_ws;
    float* out = (float*)d_out;

    k_pre<<<770, 256, 0, stream>>>(mass, vel, e_w1, e_b1, e_w2, e_b2,
                                   m_w1, m_b1, m_w2, m_b2,
                                   s_w1, s_b1, s_w2, s_b2, ws);
    dim3 grid(16, 16, 8);
    k_main<<<grid, 256, 0, stream>>>(mass, minit, solver, ws, out);
}

// Round 6
// 30.809 us; speedup vs baseline: 1.1447x; 1.1447x over previous
//
#include <hip/hip_runtime.h>
#include <hip/hip_fp16.h>
#include <math.h>

// Problem: B=8, H=W=256, C=10 metric channels, all fp32.
// ws layout: float[0..255] = per-block partial maxes of mass;
//            half[] at ws+1024 floats: 8*257*10 LUT of T(mass), stride 10.
#define GH 256
#define GW 256
#define NC 10
#define NKNOT 257

__device__ __forceinline__ float gelu_exact(float x) {
    return 0.5f * x * (1.0f + erff(x * 0.70710678118654752f));
}
__device__ __forceinline__ float softplus_f(float x) {
    if (x > 20.f) return x;
    return log1pf(expf(x));
}

// ---- Kernel 1: blocks 0..513 build LUT (one wave per (batch,knot));
//      blocks 514..769 compute partial max of mass (float4 loads).
__global__ __launch_bounds__(256) void k_pre(
        const float* __restrict__ mass,
        const float* __restrict__ vel,
        const float* __restrict__ e_w1, const float* __restrict__ e_b1,
        const float* __restrict__ e_w2, const float* __restrict__ e_b2,
        const float* __restrict__ m_w1, const float* __restrict__ m_b1,
        const float* __restrict__ m_w2, const float* __restrict__ m_b2,
        const float* __restrict__ s_w1, const float* __restrict__ s_b1,
        const float* __restrict__ s_w2, const float* __restrict__ s_b2,
        float* __restrict__ ws) {
    const int tid = threadIdx.x;
    if (blockIdx.x >= 514) {  // ---- partial max over mass
        const int pb = blockIdx.x - 514;           // 0..255
        const float4* mass4 = (const float4*)mass; // 131072 float4 total
        int base = pb * 512 + tid;                 // 512 float4 per block
        float4 a = mass4[base];
        float4 c = mass4[base + 256];
        float v = fmaxf(fmaxf(fmaxf(a.x, a.y), fmaxf(a.z, a.w)),
                        fmaxf(fmaxf(c.x, c.y), fmaxf(c.z, c.w)));
        #pragma unroll
        for (int off = 32; off > 0; off >>= 1)
            v = fmaxf(v, __shfl_xor(v, off, 64));
        __shared__ float sred[4];
        if ((tid & 63) == 0) sred[tid >> 6] = v;
        __syncthreads();
        if (tid == 0)
            ws[pb] = fmaxf(fmaxf(sred[0], sred[1]), fmaxf(sred[2], sred[3]));
        return;
    }
    // ---- LUT build: wave-parallel over hidden dim
    const int wave = blockIdx.x * 4 + (tid >> 6);   // 0..2055 == 8*257-1
    const int lane = tid & 63;
    const int b = wave / NKNOT, knot = wave % NKNOT;
    const float m = (float)knot * (1.0f / 256.0f);
    const float vx = vel[b * 3 + 0], vy = vel[b * 3 + 1], vz = vel[b * 3 + 2];

    float acc[10];
    {   // energy hidden unit `lane`
        float pre = m * e_w1[lane] + vx * e_w1[64 + lane] + vy * e_w1[128 + lane]
                  + vz * e_w1[192 + lane] + e_b1[lane];
        acc[0] = gelu_exact(pre) * e_w2[lane];
    }
    {   // momentum hidden unit `lane`
        float pre = m * m_w1[lane] + vx * m_w1[64 + lane] + vy * m_w1[128 + lane]
                  + vz * m_w1[192 + lane] + m_b1[lane];
        float h = gelu_exact(pre);
        acc[1] = h * m_w2[lane * 3 + 0];
        acc[2] = h * m_w2[lane * 3 + 1];
        acc[3] = h * m_w2[lane * 3 + 2];
    }
    {   // stress hidden units `lane`, `lane+64`
        float pre0 = m * s_w1[lane] + vx * s_w1[128 + lane] + vy * s_w1[256 + lane]
                   + vz * s_w1[384 + lane] + s_b1[lane];
        float pre1 = m * s_w1[64 + lane] + vx * s_w1[192 + lane] + vy * s_w1[320 + lane]
                   + vz * s_w1[448 + lane] + s_b1[64 + lane];
        float h0 = gelu_exact(pre0), h1 = gelu_exact(pre1);
        #pragma unroll
        for (int k = 0; k < 6; k++)
            acc[4 + k] = h0 * s_w2[lane * 6 + k] + h1 * s_w2[(lane + 64) * 6 + k];
    }
    #pragma unroll
    for (int c = 0; c < 10; c++) {
        float v = acc[c];
        #pragma unroll
        for (int off = 32; off > 0; off >>= 1)
            v += __shfl_xor(v, off, 64);
        acc[c] = v;
    }
    if (lane == 0) {
        __half* lut = (__half*)(ws + 1024) + (size_t)(b * NKNOT + knot) * NC;
        lut[0] = __float2half_rn(softplus_f(acc[0] + e_b2[0]));
        lut[1] = __float2half_rn(acc[1] + m_b2[0]);
        lut[2] = __float2half_rn(acc[2] + m_b2[1]);
        lut[3] = __float2half_rn(acc[3] + m_b2[2]);
        #pragma unroll
        for (int k = 0; k < 6; k++)
            lut[4 + k] = __float2half_rn(acc[4 + k] + s_b2[k]);
    }
}

// ---- Kernel 2: 16x16 tile, balanced per-pixel stage2 (R2 structure),
// coalesced global I/O via LDS staging, fp16 LUT. 20.4 KB LDS -> 6 blocks/CU.
__global__ __launch_bounds__(256, 6) void k_main(const float* __restrict__ mass,
                                                 const float* __restrict__ minit,
                                                 const float* __restrict__ solver,
                                                 const float* __restrict__ ws,
                                                 float* __restrict__ out) {
    const int b = blockIdx.z;
    const int tid = threadIdx.x;
    const int tile_x = blockIdx.x * 16, tile_y = blockIdx.y * 16;

    __shared__ float   s_mass[24][24];                     // 2.3 KB, halo 4
    __shared__ __half2 s_luth[NKNOT * 5];                  // 5.1 KB
    __shared__ __align__(16) float2 s_met2[5][18][18];     // 13.0 KB, halo 1
    __shared__ float   s_wmax[4];

    // --- phase 0: all global loads, all coalesced ---
    {   // finalize global max (256 partials, 1/thread)
        float v = ws[tid];
        #pragma unroll
        for (int off = 32; off > 0; off >>= 1)
            v = fmaxf(v, __shfl_xor(v, off, 64));
        if ((tid & 63) == 0) s_wmax[tid >> 6] = v;
    }
    {   // LUT: 1285 contiguous half2
        const __half2* lutg = (const __half2*)((const __half*)(ws + 1024)
                                               + (size_t)b * NKNOT * NC);
        for (int i = tid; i < NKNOT * 5; i += 256) s_luth[i] = lutg[i];
    }
    {   // minit region 18x18 px, linear coalesced read -> scatter into s_met2.
        // met2 starts as minit (metric accumulates in place); 0 outside image.
        const float* mb = minit + (size_t)b * GH * GW * NC;
        for (int i = tid; i < 18 * 90; i += 256) {
            int r = i / 90, c2 = i % 90;        // c2 = px*5 + cp
            int px = c2 / 5, cp = c2 % 5;
            int gy = tile_y - 1 + r, gx = tile_x - 1 + px;
            float2 v = make_float2(0.f, 0.f);
            if ((unsigned)gy < GH && (unsigned)gx < GW)
                v = *(const float2*)(mb + ((size_t)gy * GW + gx) * NC + cp * 2);
            s_met2[cp][r][px] = v;
        }
    }
    {   // mass tile 24x24 (12 float2/row; gx even -> pair all-in or all-out)
        const float* massb = mass + (size_t)b * GH * GW;
        for (int i = tid; i < 24 * 12; i += 256) {
            int my = i / 12, jx = i % 12;
            int gy = tile_y - 4 + my, gx = tile_x - 4 + 2 * jx;
            float2 v = make_float2(0.f, 0.f);
            if ((unsigned)gy < GH && (unsigned)gx < GW)
                v = *(const float2*)(massb + gy * GW + gx);
            *(float2*)&s_mass[my][2 * jx] = v;
        }
    }
    // softmax(solver_params)
    float p0 = solver[0], p1 = solver[1], p2 = solver[2];
    float pm = fmaxf(p0, fmaxf(p1, p2));
    float e0 = expf(p0 - pm), e1 = expf(p1 - pm), e2 = expf(p2 - pm);
    float inv = 1.f / (e0 + e1 + e2);
    float w0 = e0 * inv, w1 = e1 * inv, w2 = e2 * inv;

    __syncthreads();

    const float gmax = fmaxf(fmaxf(s_wmax[0], s_wmax[1]), fmaxf(s_wmax[2], s_wmax[3]));
    const float k0 = -25.132741228718345f * w0;          // w0 * (-8*pi*G/c^4)
    const float potscale = 2.f * w1 / (gmax + 1e-8f);    // folds mass normalization

    // --- stage 2: one region pixel per item (324 items, balanced) ---
    for (int idx = tid; idx < 18 * 18; idx += 256) {
        const int ry = idx / 18, rx = idx % 18;
        const int gy = tile_y + ry - 1, gx = tile_x + rx - 1;
        if ((unsigned)gy >= GH || (unsigned)gx >= GW) continue;  // stays 0
        const int cy = ry + 3, cx = rx + 3;
        const float m = s_mass[cy][cx];
        // 7x7 Green conv, symmetric-paired: w(dy,dx) == w(-dy,-dx)
        float pot = 0.f;
        #pragma unroll
        for (int dy = 0; dy <= 3; dy++) {
            #pragma unroll
            for (int dx = -3; dx <= 3; dx++) {
                if (dy == 0 && dx <= 0) continue;
                const float wgt = -0.15915494309189535f /
                                  __builtin_sqrtf((float)(dy * dy + dx * dx));
                pot += wgt * (s_mass[cy + dy][cx + dx] + s_mass[cy - dy][cx - dx]);
            }
        }
        const float potterm = potscale * pot;
        // fp16 LUT lerp
        float x = m * 256.f;
        int i0 = (int)x;
        i0 = i0 < 255 ? i0 : 255;
        const float f = x - (float)i0;
        const __half2* L0 = &s_luth[i0 * 5];
        #pragma unroll
        for (int cp = 0; cp < 5; cp++) {
            float2 t0 = __half22float2(L0[cp]);
            float2 t1 = __half22float2(L0[cp + 5]);
            float2 r = s_met2[cp][ry][rx];          // starts as minit
            r.x = fmaf(k0, fmaf(f, t1.x - t0.x, t0.x), r.x);
            r.y = fmaf(k0, fmaf(f, t1.y - t0.y, t0.y), r.y);
            if (cp == 2) r.x += potterm;              // c4
            if (cp == 3) r.y += potterm;              // c7
            if (cp == 0) r.x = fminf(r.x, -0.1f);     // c0
            if (cp == 2) r.x = fmaxf(r.x, 0.1f);      // c4
            if (cp == 3) r.y = fmaxf(r.y, 0.1f);      // c7
            if (cp == 4) r.y = fmaxf(r.y, 0.1f);      // c9
            s_met2[cp][ry][rx] = r;
        }
    }
    __syncthreads();

    // --- stage 3: per-thread pixel, 3x3 smooth into registers ---
    const int oy = tid >> 4, ox = tid & 15;
    const float g0 = 0.274068619f, g1 = 0.451862761f;
    const bool do_smooth = (w2 > 0.1f);
    float2 res[5];
    #pragma unroll
    for (int cp = 0; cp < 5; cp++) {
        if (do_smooth) {
            float2 a0 = s_met2[cp][oy][ox],     a1 = s_met2[cp][oy][ox + 1],     a2 = s_met2[cp][oy][ox + 2];
            float2 b0 = s_met2[cp][oy + 1][ox], b1 = s_met2[cp][oy + 1][ox + 1], b2 = s_met2[cp][oy + 1][ox + 2];
            float2 c0 = s_met2[cp][oy + 2][ox], c1 = s_met2[cp][oy + 2][ox + 1], c2 = s_met2[cp][oy + 2][ox + 2];
            float r0x = fmaf(g0, a0.x + a2.x, g1 * a1.x);
            float r0y = fmaf(g0, a0.y + a2.y, g1 * a1.y);
            float r1x = fmaf(g0, b0.x + b2.x, g1 * b1.x);
            float r1y = fmaf(g0, b0.y + b2.y, g1 * b1.y);
            float r2x = fmaf(g0, c0.x + c2.x, g1 * c1.x);
            float r2y = fmaf(g0, c0.y + c2.y, g1 * c1.y);
            res[cp].x = fmaf(g0, r0x + r2x, g1 * r1x);
            res[cp].y = fmaf(g0, r0y + r2y, g1 * r1y);
        } else {
            res[cp] = s_met2[cp][oy + 1][ox + 1];
        }
    }
    __syncthreads();   // all reads of s_met2 done

    // scatter results into s_met2 memory re-used as linear out tile
    {
        float2* s_out2 = &s_met2[0][0][0];      // 1280 float2 needed, 1620 avail
        #pragma unroll
        for (int cp = 0; cp < 5; cp++)
            s_out2[(oy * 16 + ox) * 5 + cp] = res[cp];
    }
    __syncthreads();

    // --- phase 4: coalesced float4 copy LDS -> out (16 rows x 40 float4) ---
    {
        const float4* s_out4 = (const float4*)&s_met2[0][0][0];
        float* ob = out + ((size_t)(b * GH + tile_y) * GW + tile_x) * NC;
        for (int i = tid; i < 16 * 40; i += 256) {
            int r = i / 40, c4 = i % 40;
            *(float4*)(ob + (size_t)r * GW * NC + c4 * 4) = s_out4[r * 40 + c4];
        }
    }
}

extern "C" void kernel_launch(void* const* d_in, const int* in_sizes, int n_in,
                              void* d_out, int out_size, void* d_ws, size_t ws_size,
                              hipStream_t stream) {
    const float* mass   = (const float*)d_in[0];
    const float* vel    = (const float*)d_in[1];
    const float* minit  = (const float*)d_in[2];
    const float* e_w1   = (const float*)d_in[3];
    const float* e_b1   = (const float*)d_in[4];
    const float* e_w2   = (const float*)d_in[5];
    const float* e_b2   = (const float*)d_in[6];
    const float* m_w1   = (const float*)d_in[7];
    const float* m_b1   = (const float*)d_in[8];
    const float* m_w2   = (const float*)d_in[9];
    const float* m_b2   = (const float*)d_in[10];
    const float* s_w1   = (const float*)d_in[11];
    const float* s_b1   = (const float*)d_in[12];
    const float* s_w2   = (const float*)d_in[13];
    const float* s_b2   = (const float*)d_in[14];
    const float* solver = (const float*)d_in[15];
    float* ws  = (float*)d_ws;
    float* out = (float*)d_out;

    k_pre<<<770, 256, 0, stream>>>(mass, vel, e_w1, e_b1, e_w2, e_b2,
                                   m_w1, m_b1, m_w2, m_b2,
                                   s_w1, s_b1, s_w2, s_b2, ws);
    dim3 grid(16, 16, 8);
    k_main<<<grid, 256, 0, stream>>>(mass, minit, solver, ws, out);
}